// Round 12
// baseline (2400.890 us; speedup 1.0000x reference)
//
#include <hip/hip_runtime.h>
#include <cstdint>
#include <cstddef>
#include <type_traits>
#include <utility>

typedef unsigned short u16;
typedef short short8 __attribute__((ext_vector_type(8)));
typedef __bf16 bf16x8 __attribute__((ext_vector_type(8)));
typedef float float4v __attribute__((ext_vector_type(4)));

// ---------- bf16 <-> f32 ----------
__device__ __forceinline__ float bf2f(u16 u) {
  union { uint32_t i; float f; } v; v.i = ((uint32_t)u) << 16; return v.f;
}
__device__ __forceinline__ u16 f2bf(float f) {
  union { uint32_t i; float f; } v; v.f = f;
  uint32_t u = v.i;
  return (u16)((u + 0x7FFFu + ((u >> 16) & 1u)) >> 16);
}

// ---------- fast transcendentals (saturate cleanly at +-inf) ----------
__device__ __forceinline__ float fsig(float x) {
  float e = __expf(-x);
  return __builtin_amdgcn_rcpf(1.0f + e);
}
__device__ __forceinline__ float ftanh(float x) {
  float e = __expf(2.0f * x);
  return 1.0f - 2.0f * __builtin_amdgcn_rcpf(e + 1.0f);
}

// ---------- async global->LDS (16B/lane). LDS dest must be wave-uniform
// base + lane*16 (guide: m104); our staging layout satisfies this. ----------
__device__ __forceinline__ void gl_lds16(const void* g, void* l) {
  __builtin_amdgcn_global_load_lds(
      (const __attribute__((address_space(1))) uint32_t*)(uintptr_t)g,
      (__attribute__((address_space(3))) uint32_t*)(uintptr_t)l, 16, 0, 0);
}

// ---------- MFMA wrapper: works whether builtin takes short8 or bf16x8 ----------
template <class V, class = void> struct MfmaTakesShort : std::false_type {};
template <class V>
struct MfmaTakesShort<V, std::void_t<decltype(__builtin_amdgcn_mfma_f32_16x16x32_bf16(
    std::declval<V>(), std::declval<V>(), std::declval<float4v>(), 0, 0, 0))>>
    : std::true_type {};

template <bool UseShort> struct MF {
  template <class V>
  static __device__ __forceinline__ float4v run(V a, V b, float4v c) {
    return __builtin_amdgcn_mfma_f32_16x16x32_bf16(a, b, c, 0, 0, 0);
  }
};
template <> struct MF<false> {
  template <class V>
  static __device__ __forceinline__ float4v run(V a, V b, float4v c) {
    return __builtin_amdgcn_mfma_f32_16x16x32_bf16(
        __builtin_bit_cast(bf16x8, a), __builtin_bit_cast(bf16x8, b), c, 0, 0, 0);
  }
};
__device__ __forceinline__ float4v mfma_bf16(short8 a, short8 b, float4v c) {
  return MF<MfmaTakesShort<short8>::value>::run(a, b, c);
}

// ============================================================================
// Weight conversion: f32 [2048][Kin] -> bf16 [2048][512], zero-padded
// ============================================================================
__global__ void k_cvt_wih(const float* __restrict__ w, u16* __restrict__ o, int Kin) {
  int id = blockIdx.x * 256 + threadIdx.x;   // 2048*512 total
  int n = id >> 9, k = id & 511;
  o[id] = (k < Kin) ? f2bf(w[(long)n * Kin + k]) : (u16)0;
}

// f32 -> bf16 straight convert (w_hh: 2*1024*256 = 524288 elems)
__global__ void k_cvt_whh(const float* __restrict__ w, u16* __restrict__ o) {
  int id = blockIdx.x * 256 + threadIdx.x;
  o[id] = f2bf(w[id]);
}

// ============================================================================
// proj[v][k][nf] = sum_cd emb_char[v][cd] * conv_w[nf][cd][k]   (f32 in, bf16 out)
// ============================================================================
__global__ void k_proj(const float* __restrict__ ec, const float* __restrict__ cw,
                       u16* __restrict__ proj) {
  int v = blockIdx.x, idx = threadIdx.x;
  if (idx >= 300) return;
  int k = idx / 100, nf = idx % 100;
  float s = 0.f;
  for (int cd = 0; cd < 100; cd++)
    s += ec[v * 100 + cd] * cw[(nf * 100 + cd) * 3 + k];
  proj[v * 300 + k * 100 + nf] = f2bf(s);
}

// ============================================================================
// word + pos embedding gather into bf16 x (cols 0..299 word, 400..499 pos,
// 500..511 zero). Char features (300..399) filled by k_charconv.
// ============================================================================
__global__ void k_embed(const int* __restrict__ iw, const int* __restrict__ ip,
                        const float* __restrict__ ew, const float* __restrict__ ep,
                        u16* __restrict__ x) {
  int row = blockIdx.x, j = threadIdx.x;
  u16 v;
  if (j < 300) v = f2bf(ew[(long)iw[row] * 300 + j]);
  else if (j < 400) return;
  else if (j < 500) v = f2bf(ep[ip[row] * 100 + (j - 400)]);
  else v = 0;
  x[row * 512 + j] = v;
}

// ============================================================================
// char conv via proj table in LDS: out[nf] = tanh(b + max_p sum_k proj)
// ============================================================================
__global__ __launch_bounds__(128) void k_charconv(const int* __restrict__ ic,
                                                  const u16* __restrict__ proj,
                                                  const float* __restrict__ cb,
                                                  u16* __restrict__ x) {
  __shared__ u16 pl[30000];
  __shared__ int ids[20];
  int tid = threadIdx.x;
  for (int i = tid; i < 15000; i += 128)
    ((uint32_t*)pl)[i] = ((const uint32_t*)proj)[i];
  float bias = (tid < 100) ? cb[tid] : 0.f;
  for (int r = 0; r < 16; r++) {
    int row = blockIdx.x * 16 + r;
    __syncthreads();  // covers pl load on first iter; protects ids reuse
    if (tid < 20) ids[tid] = ic[row * 20 + tid];
    __syncthreads();
    if (tid < 100) {
      float mx = -1e30f;
      for (int p = 0; p < 22; p++) {
        float s = 0.f;
#pragma unroll
        for (int k = 0; k < 3; k++) {
          int q = p + k - 2;
          if (q >= 0 && q < 20) s += bf2f(pl[ids[q] * 300 + k * 100 + tid]);
        }
        mx = fmaxf(mx, s);
      }
      x[row * 512 + 300 + tid] = f2bf(ftanh(mx + bias));
    }
  }
}

// ============================================================================
// GEMM  C[16384 x 2048] = A[16384 x 512](bf16) @ B[2048 x 512]^T + bias(f32)
// 128x128 tile, BK=64, 4 waves, 16x16x32 MFMA. C fp32 (tier A) or bf16 (tier B).
// global_load_lds width=16 staging + XCD-aware bijective swizzle (R10:
// measured neutral vs R8's plain staging, kept on theory grounds).
// ============================================================================
template <bool GXF32>
__global__ __launch_bounds__(256) void k_gemm(const u16* __restrict__ A,
                                              const u16* __restrict__ Bm,
                                              const float* __restrict__ bias,
                                              void* __restrict__ Cv) {
  __shared__ u16 lA[128 * 64];
  __shared__ u16 lB[128 * 64];
  int tid = threadIdx.x;
  int w = tid >> 6, l = tid & 63, q = l >> 4, c16 = l & 15;
  int wm = w >> 1, wn = w & 1;
  int lin = blockIdx.y * gridDim.x + blockIdx.x;
  int swz = (lin & 7) * 256 + (lin >> 3);
  int m0 = (swz >> 4) * 128, n0 = (swz & 15) * 128;
  float4v acc[4][4];
#pragma unroll
  for (int i = 0; i < 4; i++)
#pragma unroll
    for (int j = 0; j < 4; j++) acc[i][j] = (float4v){0.f, 0.f, 0.f, 0.f};

  for (int kk = 0; kk < 512; kk += 64) {
    __syncthreads();
#pragma unroll
    for (int j = 0; j < 4; j++) {
      int idx = j * 256 + tid;
      int m = idx >> 3, k8 = (idx & 7) * 8;
      gl_lds16(A + (long)(m0 + m) * 512 + kk + k8, lA + idx * 8);
      gl_lds16(Bm + (long)(n0 + m) * 512 + kk + k8, lB + idx * 8);
    }
    __syncthreads();  // vmcnt(0) drain covers the async LDS loads
#pragma unroll
    for (int kt = 0; kt < 2; kt++) {
      short8 af[4], bfv[4];
#pragma unroll
      for (int mt = 0; mt < 4; mt++)
        af[mt] = *(const short8*)(lA + (wm * 64 + mt * 16 + c16) * 64 + kt * 32 + q * 8);
#pragma unroll
      for (int nt = 0; nt < 4; nt++)
        bfv[nt] = *(const short8*)(lB + (wn * 64 + nt * 16 + c16) * 64 + kt * 32 + q * 8);
#pragma unroll
      for (int mt = 0; mt < 4; mt++)
#pragma unroll
        for (int nt = 0; nt < 4; nt++)
          acc[mt][nt] = mfma_bf16(af[mt], bfv[nt], acc[mt][nt]);
    }
  }
#pragma unroll
  for (int mt = 0; mt < 4; mt++)
#pragma unroll
    for (int nt = 0; nt < 4; nt++) {
      int ng = n0 + wn * 64 + nt * 16 + c16;
      float bv = bias[ng];
#pragma unroll
      for (int r = 0; r < 4; r++) {
        long mg = m0 + wm * 64 + mt * 16 + q * 4 + r;
        float val = acc[mt][nt][r] + bv;
        if constexpr (GXF32) ((float*)Cv)[mg * 2048 + ng] = val;
        else ((u16*)Cv)[mg * 2048 + ng] = f2bf(val);
      }
    }
}

// ============================================================================
// LSTM recurrence — R8 skeleton + STAGGERED PAIRWISE VALIDATION (R11).
// COLUMN-SPLIT + SPLIT-K + SWAPPED-OPERAND MFMA + SENTINEL-IN-DATA EXCHANGE.
// 16 blocks = 8 pairs (4 bg x 2 dir) x 2 halves; each block owns 128 h-cols.
//
// R11 change (ph2/ph3 only; addresses/protocol byte-identical to R8's
// verified 632us): the monolithic __all over all 8 ingest values waited on
// the NEWEST of 8 loads (vmcnt(0)-class) and a failed check re-issued all 8
// LLC loads (~600-700cy each retry; timing math says ~50% of steps retried
// and every step ate a ~200-300cy tail wait). Now validation is 4 interleaved
// {check pair k -> 4 MFMAs} stages: compiler emits partial waits
// (vmcnt(6)->4->2->0 equivalent), each pair's check is pushed later by the
// preceding MFMAs (progressive cover), and a retry re-issues only the 2
// missing loads. Protocol safety unchanged: per-pair capped retry loops
// (bug -> NaN ingested -> absmax fail, never hang).
//  - hn64 packs 4 bf16; fsig/ftanh saturate so hn is always finite and
//    f2bf(finite) is never 0xFFFF -> u64 ~0 is an unreachable SENTINEL.
//  - hx = 4-slot ring (slot s&3), memset 0xFF per dispatch. Producer stores
//    fire-and-forget (relaxed agent atomic). No flag, no ack.
//  - Post-barrier sentinel restore of the consumed slot (512 thr = 512 u64);
//    producer rewrites 3 steps later, mutual data-dependence bounds skew.
//  - lgkm-only barrier per step; no vmcnt drain in the loop.
// ============================================================================
template <bool GXF32, bool OUTF32>
__global__ __launch_bounds__(512, 2) void k_recur(
    const void* __restrict__ gxv, const u16* __restrict__ whh,
    const float* __restrict__ mask, void* __restrict__ outv,
    unsigned long long* __restrict__ hx) {
  __shared__ u16 hls[2][16 * 136];  // own half only, [row][col] row-major
  int tid = threadIdx.x;
  int w = tid >> 6, l = tid & 63;
  int row = l & 15;        // batch row within block (D col = l&15)
  int cg = l >> 4;         // col-group; lane owns cols c4..c4+3 of its tile
  int c4 = cg * 4;
  int blk = blockIdx.x;
  int pair = blk & 7, half = blk >> 3;
  int bg = pair >> 1, d = pair & 1;
  int b0 = bg * 16;
  int ht = half * 8 + w;                 // global h-coltile 0..15
  const u16* Wd = whh + d * (1024 * 256);
  constexpr unsigned long long SEN = ~0ull;

  for (int i = tid; i < 16 * 136; i += 512) hls[0][i] = 0;

  // Weight fragments: [g*8+j], j<4 own-half k-tiles, j>=4 partner-half.
  short8 Breg[32];
#pragma unroll
  for (int g = 0; g < 4; g++)
#pragma unroll
    for (int j = 0; j < 8; j++) {
      int ktg = (j < 4) ? (half * 4 + j) : ((half ^ 1) * 4 + (j - 4));
      Breg[g * 8 + j] =
          *(const short8*)(Wd + ((g * 16 + ht) * 16 + row) * 256 + ktg * 32 + cg * 8);
    }

  float c_[4] = {0.f, 0.f, 0.f, 0.f};
  unsigned long long hp64 = 0ull;  // this lane's previous 4 h-values (bf16 x4)
  __syncthreads();

  const float* gxf = (const float*)gxv;
  const u16* gxh = (const u16*)gxv;
  float* outf = (float*)outv;
  u16* outh = (u16*)outv;

  // lane-invariant bases
  int grow = b0 + row;                                   // global batch row
  const float* mrowp = mask + grow * 256;
  size_t gxbase = (size_t)grow * 524288 + d * 1024 + ht * 16 + c4;
  long obase = ((long)grow * 256) * 512 + d * 256 + ht * 16 + c4;

  using GxT = std::conditional_t<GXF32, float4v, unsigned long long>;
  GxT gxc[4], gxn[4];
  float mcur, mnxt;

  // preamble: load gx(t0) + mask(t0)
  {
    int t0 = d ? 255 : 0;
    mcur = mrowp[t0];
#pragma unroll
    for (int g = 0; g < 4; g++) {
      if constexpr (GXF32)
        gxc[g] = *(const float4v*)(gxf + gxbase + (size_t)t0 * 2048 + g * 256);
      else
        gxc[g] = *(const unsigned long long*)(gxh + gxbase + (size_t)t0 * 2048 + g * 256);
    }
  }

#pragma unroll 1
  for (int s = 0; s < 256; s++) {
    int t = d ? (255 - s) : s;
    const u16* hrd = hls[s & 1];
    u16* hwr = hls[(s & 1) ^ 1];

    // ---- ph0: SPECULATIVE partner ingest (validity checked pairwise) ----
    unsigned long long pv0 = 0, pv1 = 0, pv2 = 0, pv3 = 0,
                       pv4 = 0, pv5 = 0, pv6 = 0, pv7 = 0;
    const unsigned long long* ps = nullptr;
    if (s > 0) {
      ps = hx + ((size_t)(((s - 1) & 3) * 8 + pair) * 2 + (half ^ 1)) * 512;
      pv0 = __hip_atomic_load(&ps[(0 * 8 + cg * 2 + 0) * 16 + row], __ATOMIC_RELAXED, __HIP_MEMORY_SCOPE_AGENT);
      pv1 = __hip_atomic_load(&ps[(0 * 8 + cg * 2 + 1) * 16 + row], __ATOMIC_RELAXED, __HIP_MEMORY_SCOPE_AGENT);
      pv2 = __hip_atomic_load(&ps[(1 * 8 + cg * 2 + 0) * 16 + row], __ATOMIC_RELAXED, __HIP_MEMORY_SCOPE_AGENT);
      pv3 = __hip_atomic_load(&ps[(1 * 8 + cg * 2 + 1) * 16 + row], __ATOMIC_RELAXED, __HIP_MEMORY_SCOPE_AGENT);
      pv4 = __hip_atomic_load(&ps[(2 * 8 + cg * 2 + 0) * 16 + row], __ATOMIC_RELAXED, __HIP_MEMORY_SCOPE_AGENT);
      pv5 = __hip_atomic_load(&ps[(2 * 8 + cg * 2 + 1) * 16 + row], __ATOMIC_RELAXED, __HIP_MEMORY_SCOPE_AGENT);
      pv6 = __hip_atomic_load(&ps[(3 * 8 + cg * 2 + 0) * 16 + row], __ATOMIC_RELAXED, __HIP_MEMORY_SCOPE_AGENT);
      pv7 = __hip_atomic_load(&ps[(3 * 8 + cg * 2 + 1) * 16 + row], __ATOMIC_RELAXED, __HIP_MEMORY_SCOPE_AGENT);
    }
    __builtin_amdgcn_sched_barrier(0);  // loads issued before the MFMA body

    // ---- ph1: own-half-K MFMA (W as A, h as B); covers ingest latency ----
    float4v acc[4];
#pragma unroll
    for (int g = 0; g < 4; g++) acc[g] = (float4v){0.f, 0.f, 0.f, 0.f};
#pragma unroll
    for (int ktl = 0; ktl < 4; ktl++) {
      short8 b = *(const short8*)(hrd + row * 136 + ktl * 32 + cg * 8);
#pragma unroll
      for (int g = 0; g < 4; g++)
        acc[g] = mfma_bf16(Breg[g * 8 + ktl], b, acc[g]);
    }

    // ---- ph2+ph3: STAGGERED pairwise validate -> partner MFMA.
    // Pair k's check waits only its own (older) loads; each preceding MFMA
    // cluster pushes the next check later (progressive cover). Retry
    // re-issues only the missing pair (2 loads, not 8).
    if (s > 0) {
      union U { unsigned long long u[2]; short8 s8; };
      {  // pair 0 -> k-tile 4
        unsigned cnt = 0;
        while (!__all(pv0 != SEN && pv1 != SEN)) {
          if (++cnt > 400000u) break;  // ingests NaN -> absmax fail, no hang
          __builtin_amdgcn_s_sleep(1);
          pv0 = __hip_atomic_load(&ps[(0 * 8 + cg * 2 + 0) * 16 + row], __ATOMIC_RELAXED, __HIP_MEMORY_SCOPE_AGENT);
          pv1 = __hip_atomic_load(&ps[(0 * 8 + cg * 2 + 1) * 16 + row], __ATOMIC_RELAXED, __HIP_MEMORY_SCOPE_AGENT);
        }
        U uu; uu.u[0] = pv0; uu.u[1] = pv1;
#pragma unroll
        for (int g = 0; g < 4; g++) acc[g] = mfma_bf16(Breg[g * 8 + 4], uu.s8, acc[g]);
      }
      {  // pair 1 -> k-tile 5
        unsigned cnt = 0;
        while (!__all(pv2 != SEN && pv3 != SEN)) {
          if (++cnt > 400000u) break;
          __builtin_amdgcn_s_sleep(1);
          pv2 = __hip_atomic_load(&ps[(1 * 8 + cg * 2 + 0) * 16 + row], __ATOMIC_RELAXED, __HIP_MEMORY_SCOPE_AGENT);
          pv3 = __hip_atomic_load(&ps[(1 * 8 + cg * 2 + 1) * 16 + row], __ATOMIC_RELAXED, __HIP_MEMORY_SCOPE_AGENT);
        }
        U uu; uu.u[0] = pv2; uu.u[1] = pv3;
#pragma unroll
        for (int g = 0; g < 4; g++) acc[g] = mfma_bf16(Breg[g * 8 + 5], uu.s8, acc[g]);
      }
      {  // pair 2 -> k-tile 6
        unsigned cnt = 0;
        while (!__all(pv4 != SEN && pv5 != SEN)) {
          if (++cnt > 400000u) break;
          __builtin_amdgcn_s_sleep(1);
          pv4 = __hip_atomic_load(&ps[(2 * 8 + cg * 2 + 0) * 16 + row], __ATOMIC_RELAXED, __HIP_MEMORY_SCOPE_AGENT);
          pv5 = __hip_atomic_load(&ps[(2 * 8 + cg * 2 + 1) * 16 + row], __ATOMIC_RELAXED, __HIP_MEMORY_SCOPE_AGENT);
        }
        U uu; uu.u[0] = pv4; uu.u[1] = pv5;
#pragma unroll
        for (int g = 0; g < 4; g++) acc[g] = mfma_bf16(Breg[g * 8 + 6], uu.s8, acc[g]);
      }
      {  // pair 3 -> k-tile 7
        unsigned cnt = 0;
        while (!__all(pv6 != SEN && pv7 != SEN)) {
          if (++cnt > 400000u) break;
          __builtin_amdgcn_s_sleep(1);
          pv6 = __hip_atomic_load(&ps[(3 * 8 + cg * 2 + 0) * 16 + row], __ATOMIC_RELAXED, __HIP_MEMORY_SCOPE_AGENT);
          pv7 = __hip_atomic_load(&ps[(3 * 8 + cg * 2 + 1) * 16 + row], __ATOMIC_RELAXED, __HIP_MEMORY_SCOPE_AGENT);
        }
        U uu; uu.u[0] = pv6; uu.u[1] = pv7;
#pragma unroll
        for (int g = 0; g < 4; g++) acc[g] = mfma_bf16(Breg[g * 8 + 7], uu.s8, acc[g]);
      }
    }

    // ---- ph4: nonlinearity; lane owns row `grow`, h-cols ht*16+c4..+3 ----
    float mt = mcur, mo = 1.f - mcur;
    float hnv[4];
    unsigned long long hn64 = 0ull;
#pragma unroll
    for (int r = 0; r < 4; r++) {
      float gi, gf, gg, go;
      if constexpr (GXF32) {
        gi = gxc[0][r]; gf = gxc[1][r]; gg = gxc[2][r]; go = gxc[3][r];
      } else {
        gi = bf2f((u16)(gxc[0] >> (r * 16)));
        gf = bf2f((u16)(gxc[1] >> (r * 16)));
        gg = bf2f((u16)(gxc[2] >> (r * 16)));
        go = bf2f((u16)(gxc[3] >> (r * 16)));
      }
      float iv = fsig(acc[0][r] + gi);
      float fv = fsig(acc[1][r] + gf);
      float gv = ftanh(acc[2][r] + gg);
      float ov = fsig(acc[3][r] + go);
      float hpo = bf2f((u16)(hp64 >> (r * 16)));
      float cn = fv * c_[r] + iv * gv;
      float hn = ov * ftanh(cn);
      hn = mt * hn + mo * hpo;
      cn = mt * cn + mo * c_[r];
      c_[r] = cn;
      hnv[r] = hn;
      hn64 |= ((unsigned long long)f2bf(hn)) << (r * 16);
    }

    // ---- ph5: publish h(s), outputs, prefetch gx(t+1), restore sentinel ---
    if (s < 255) {
      // hx store: fire-and-forget (relaxed atomic -> LLC; data IS the signal)
      __hip_atomic_store(
          &hx[((size_t)((s & 3) * 8 + pair) * 2 + half) * 512 + (w * 4 + cg) * 16 + row],
          hn64, __ATOMIC_RELAXED, __HIP_MEMORY_SCOPE_AGENT);
      // own h -> hls (one b64; read by next step's ph1 b128s)
      *(unsigned long long*)(hwr + row * 136 + w * 16 + c4) = hn64;
      // output store (single vector op)
      if constexpr (OUTF32) {
        float4v ov4 = {hnv[0], hnv[1], hnv[2], hnv[3]};
        *(float4v*)(outf + obase + (long)t * 512) = ov4;
      } else {
        *(unsigned long long*)(outh + obase + (long)t * 512) = hn64;
      }
      // prefetch next-step gx + mask (consumed next ph4; ~full-step cover)
      int tn = d ? (254 - s) : (s + 1);
      mnxt = mrowp[tn];
#pragma unroll
      for (int g = 0; g < 4; g++) {
        if constexpr (GXF32)
          gxn[g] = *(const float4v*)(gxf + gxbase + (size_t)tn * 2048 + g * 256);
        else
          gxn[g] = *(const unsigned long long*)(gxh + gxbase + (size_t)tn * 2048 + g * 256);
      }
      __builtin_amdgcn_sched_barrier(0);
      // lgkm-only barrier: hls visibility; NO vmcnt drain in the loop
      asm volatile("s_waitcnt lgkmcnt(0)" ::: "memory");
      __builtin_amdgcn_s_barrier();
      __builtin_amdgcn_sched_barrier(0);
      // restore sentinel on the slot consumed this step (all waves are past
      // their ingest-check: the barrier above proves it). 512 thr = 512 u64.
      if (s > 0) {
        __hip_atomic_store(
            &hx[((size_t)(((s - 1) & 3) * 8 + pair) * 2 + (half ^ 1)) * 512 + tid],
            SEN, __ATOMIC_RELAXED, __HIP_MEMORY_SCOPE_AGENT);
      }
#pragma unroll
      for (int g = 0; g < 4; g++) gxc[g] = gxn[g];
      mcur = mnxt;
    } else {
      // last step: outputs only
      if constexpr (OUTF32) {
        float4v ov4 = {hnv[0], hnv[1], hnv[2], hnv[3]};
        *(float4v*)(outf + obase + (long)t * 512) = ov4;
      } else {
        *(unsigned long long*)(outh + obase + (long)t * 512) = hn64;
      }
    }
    hp64 = hn64;
  }
}

// ============================================================================
extern "C" void kernel_launch(void* const* d_in, const int* in_sizes, int n_in,
                              void* d_out, int out_size, void* d_ws, size_t ws_size,
                              hipStream_t stream) {
  const int* iw = (const int*)d_in[0];
  const int* ic = (const int*)d_in[1];
  const int* ip = (const int*)d_in[2];
  const float* mask = (const float*)d_in[3];
  const float* ew = (const float*)d_in[4];
  const float* ec = (const float*)d_in[5];
  const float* ep = (const float*)d_in[6];
  const float* cw = (const float*)d_in[7];
  const float* cb = (const float*)d_in[8];
  const float* wih[3] = {(const float*)d_in[9], (const float*)d_in[12], (const float*)d_in[15]};
  const float* whh[3] = {(const float*)d_in[10], (const float*)d_in[13], (const float*)d_in[16]};
  const float* bs[3] = {(const float*)d_in[11], (const float*)d_in[14], (const float*)d_in[17]};

  char* ws = (char*)d_ws;
  size_t szX0 = (size_t)16384 * 512 * 2;
  size_t szGXf = (size_t)16384 * 2048 * 4;
  size_t szWIH = (size_t)2048 * 512 * 2;
  size_t szWHH = (size_t)2 * 1024 * 256 * 2;
  size_t szPROJ = 60032;
  size_t szHX = (size_t)4 * 8 * 2 * 4096;   // 4-slot ring x pair x half = 256KB
  bool f32gx = ws_size >= szX0 + szGXf + szWIH + szWHH + szPROJ + szHX;

  size_t off = 0;
  u16* X0 = (u16*)(ws + off); off += szX0;
  void* GX = (void*)(ws + off); off += f32gx ? szGXf : (szGXf / 2);
  u16* WIHB = (u16*)(ws + off); off += szWIH;
  u16* WHHB = (u16*)(ws + off); off += szWHH;
  u16* PROJ = (u16*)(ws + off); off += szPROJ;
  unsigned long long* HX = (unsigned long long*)(ws + off);
  u16* X1 = (u16*)d_out;  // bf16 staging in d_out; dead before final f32 write

  hipLaunchKernelGGL(k_proj, dim3(100), dim3(320), 0, stream, ec, cw, PROJ);
  hipLaunchKernelGGL(k_embed, dim3(16384), dim3(512), 0, stream, iw, ip, ew, ep, X0);
  hipLaunchKernelGGL(k_charconv, dim3(1024), dim3(128), 0, stream, ic, PROJ, cb, X0);

  const u16* Xin[3] = {X0, X1, X0};
  void* Xout[3] = {(void*)X1, (void*)X0, d_out};
  int Kin[3] = {500, 512, 512};

  for (int lyr = 0; lyr < 3; lyr++) {
    hipLaunchKernelGGL(k_cvt_wih, dim3(4096), dim3(256), 0, stream, wih[lyr], WIHB, Kin[lyr]);
    hipLaunchKernelGGL(k_cvt_whh, dim3(2048), dim3(256), 0, stream, whh[lyr], WHHB);
    hipMemsetAsync(HX, 0xFF, szHX, stream);  // all slots -> sentinel (replay-safe)
    if (f32gx) {
      hipLaunchKernelGGL((k_gemm<true>), dim3(16, 128), dim3(256), 0, stream,
                         Xin[lyr], WIHB, bs[lyr], GX);
      if (lyr < 2)
        hipLaunchKernelGGL((k_recur<true, false>), dim3(16), dim3(512), 0, stream,
                           GX, WHHB, mask, Xout[lyr], HX);
      else
        hipLaunchKernelGGL((k_recur<true, true>), dim3(16), dim3(512), 0, stream,
                           GX, WHHB, mask, Xout[lyr], HX);
    } else {
      hipLaunchKernelGGL((k_gemm<false>), dim3(16, 128), dim3(256), 0, stream,
                         Xin[lyr], WIHB, bs[lyr], GX);
      if (lyr < 2)
        hipLaunchKernelGGL((k_recur<false, false>), dim3(16), dim3(512), 0, stream,
                           GX, WHHB, mask, Xout[lyr], HX);
      else
        hipLaunchKernelGGL((k_recur<false, true>), dim3(16), dim3(512), 0, stream,
                           GX, WHHB, mask, Xout[lyr], HX);
    }
  }
}

// Round 13
// 2313.546 us; speedup vs baseline: 1.0378x; 1.0378x over previous
//
#include <hip/hip_runtime.h>
#include <cstdint>
#include <cstddef>
#include <type_traits>
#include <utility>

typedef unsigned short u16;
typedef short short8 __attribute__((ext_vector_type(8)));
typedef __bf16 bf16x8 __attribute__((ext_vector_type(8)));
typedef float float4v __attribute__((ext_vector_type(4)));

// ---------- bf16 <-> f32 ----------
__device__ __forceinline__ float bf2f(u16 u) {
  union { uint32_t i; float f; } v; v.i = ((uint32_t)u) << 16; return v.f;
}
__device__ __forceinline__ u16 f2bf(float f) {
  union { uint32_t i; float f; } v; v.f = f;
  uint32_t u = v.i;
  return (u16)((u + 0x7FFFu + ((u >> 16) & 1u)) >> 16);
}

// ---------- fast transcendentals (saturate cleanly at +-inf) ----------
__device__ __forceinline__ float fsig(float x) {
  float e = __expf(-x);
  return __builtin_amdgcn_rcpf(1.0f + e);
}
__device__ __forceinline__ float ftanh(float x) {
  float e = __expf(2.0f * x);
  return 1.0f - 2.0f * __builtin_amdgcn_rcpf(e + 1.0f);
}

// ---------- async global->LDS (16B/lane). LDS dest must be wave-uniform
// base + lane*16 (guide: m104); our staging layout satisfies this. ----------
__device__ __forceinline__ void gl_lds16(const void* g, void* l) {
  __builtin_amdgcn_global_load_lds(
      (const __attribute__((address_space(1))) uint32_t*)(uintptr_t)g,
      (__attribute__((address_space(3))) uint32_t*)(uintptr_t)l, 16, 0, 0);
}

// ---------- MFMA wrapper: works whether builtin takes short8 or bf16x8 ----------
template <class V, class = void> struct MfmaTakesShort : std::false_type {};
template <class V>
struct MfmaTakesShort<V, std::void_t<decltype(__builtin_amdgcn_mfma_f32_16x16x32_bf16(
    std::declval<V>(), std::declval<V>(), std::declval<float4v>(), 0, 0, 0))>>
    : std::true_type {};

template <bool UseShort> struct MF {
  template <class V>
  static __device__ __forceinline__ float4v run(V a, V b, float4v c) {
    return __builtin_amdgcn_mfma_f32_16x16x32_bf16(a, b, c, 0, 0, 0);
  }
};
template <> struct MF<false> {
  template <class V>
  static __device__ __forceinline__ float4v run(V a, V b, float4v c) {
    return __builtin_amdgcn_mfma_f32_16x16x32_bf16(
        __builtin_bit_cast(bf16x8, a), __builtin_bit_cast(bf16x8, b), c, 0, 0, 0);
  }
};
__device__ __forceinline__ float4v mfma_bf16(short8 a, short8 b, float4v c) {
  return MF<MfmaTakesShort<short8>::value>::run(a, b, c);
}

// ============================================================================
// Weight conversion: f32 [2048][Kin] -> bf16 [2048][512], zero-padded
// ============================================================================
__global__ void k_cvt_wih(const float* __restrict__ w, u16* __restrict__ o, int Kin) {
  int id = blockIdx.x * 256 + threadIdx.x;   // 2048*512 total
  int n = id >> 9, k = id & 511;
  o[id] = (k < Kin) ? f2bf(w[(long)n * Kin + k]) : (u16)0;
}

// f32 -> bf16 straight convert (w_hh: 2*1024*256 = 524288 elems)
__global__ void k_cvt_whh(const float* __restrict__ w, u16* __restrict__ o) {
  int id = blockIdx.x * 256 + threadIdx.x;
  o[id] = f2bf(w[id]);
}

// ============================================================================
// proj[v][k][nf] = sum_cd emb_char[v][cd] * conv_w[nf][cd][k]   (f32 in, bf16 out)
// ============================================================================
__global__ void k_proj(const float* __restrict__ ec, const float* __restrict__ cw,
                       u16* __restrict__ proj) {
  int v = blockIdx.x, idx = threadIdx.x;
  if (idx >= 300) return;
  int k = idx / 100, nf = idx % 100;
  float s = 0.f;
  for (int cd = 0; cd < 100; cd++)
    s += ec[v * 100 + cd] * cw[(nf * 100 + cd) * 3 + k];
  proj[v * 300 + k * 100 + nf] = f2bf(s);
}

// ============================================================================
// word + pos embedding gather into bf16 x (cols 0..299 word, 400..499 pos,
// 500..511 zero). Char features (300..399) filled by k_charconv.
// ============================================================================
__global__ void k_embed(const int* __restrict__ iw, const int* __restrict__ ip,
                        const float* __restrict__ ew, const float* __restrict__ ep,
                        u16* __restrict__ x) {
  int row = blockIdx.x, j = threadIdx.x;
  u16 v;
  if (j < 300) v = f2bf(ew[(long)iw[row] * 300 + j]);
  else if (j < 400) return;
  else if (j < 500) v = f2bf(ep[ip[row] * 100 + (j - 400)]);
  else v = 0;
  x[row * 512 + j] = v;
}

// ============================================================================
// char conv via proj table in LDS: out[nf] = tanh(b + max_p sum_k proj)
// ============================================================================
__global__ __launch_bounds__(128) void k_charconv(const int* __restrict__ ic,
                                                  const u16* __restrict__ proj,
                                                  const float* __restrict__ cb,
                                                  u16* __restrict__ x) {
  __shared__ u16 pl[30000];
  __shared__ int ids[20];
  int tid = threadIdx.x;
  for (int i = tid; i < 15000; i += 128)
    ((uint32_t*)pl)[i] = ((const uint32_t*)proj)[i];
  float bias = (tid < 100) ? cb[tid] : 0.f;
  for (int r = 0; r < 16; r++) {
    int row = blockIdx.x * 16 + r;
    __syncthreads();  // covers pl load on first iter; protects ids reuse
    if (tid < 20) ids[tid] = ic[row * 20 + tid];
    __syncthreads();
    if (tid < 100) {
      float mx = -1e30f;
      for (int p = 0; p < 22; p++) {
        float s = 0.f;
#pragma unroll
        for (int k = 0; k < 3; k++) {
          int q = p + k - 2;
          if (q >= 0 && q < 20) s += bf2f(pl[ids[q] * 300 + k * 100 + tid]);
        }
        mx = fmaxf(mx, s);
      }
      x[row * 512 + 300 + tid] = f2bf(ftanh(mx + bias));
    }
  }
}

// ============================================================================
// GEMM  C[16384 x 2048] = A[16384 x 512](bf16) @ B[2048 x 512]^T + bias(f32)
// 128x128 tile, BK=64, 4 waves, 16x16x32 MFMA. C fp32 (tier A) or bf16 (tier B).
// global_load_lds width=16 staging + XCD-aware bijective swizzle (R10:
// measured neutral vs plain staging, kept on theory grounds).
// ============================================================================
template <bool GXF32>
__global__ __launch_bounds__(256) void k_gemm(const u16* __restrict__ A,
                                              const u16* __restrict__ Bm,
                                              const float* __restrict__ bias,
                                              void* __restrict__ Cv) {
  __shared__ u16 lA[128 * 64];
  __shared__ u16 lB[128 * 64];
  int tid = threadIdx.x;
  int w = tid >> 6, l = tid & 63, q = l >> 4, c16 = l & 15;
  int wm = w >> 1, wn = w & 1;
  int lin = blockIdx.y * gridDim.x + blockIdx.x;
  int swz = (lin & 7) * 256 + (lin >> 3);
  int m0 = (swz >> 4) * 128, n0 = (swz & 15) * 128;
  float4v acc[4][4];
#pragma unroll
  for (int i = 0; i < 4; i++)
#pragma unroll
    for (int j = 0; j < 4; j++) acc[i][j] = (float4v){0.f, 0.f, 0.f, 0.f};

  for (int kk = 0; kk < 512; kk += 64) {
    __syncthreads();
#pragma unroll
    for (int j = 0; j < 4; j++) {
      int idx = j * 256 + tid;
      int m = idx >> 3, k8 = (idx & 7) * 8;
      gl_lds16(A + (long)(m0 + m) * 512 + kk + k8, lA + idx * 8);
      gl_lds16(Bm + (long)(n0 + m) * 512 + kk + k8, lB + idx * 8);
    }
    __syncthreads();  // vmcnt(0) drain covers the async LDS loads
#pragma unroll
    for (int kt = 0; kt < 2; kt++) {
      short8 af[4], bfv[4];
#pragma unroll
      for (int mt = 0; mt < 4; mt++)
        af[mt] = *(const short8*)(lA + (wm * 64 + mt * 16 + c16) * 64 + kt * 32 + q * 8);
#pragma unroll
      for (int nt = 0; nt < 4; nt++)
        bfv[nt] = *(const short8*)(lB + (wn * 64 + nt * 16 + c16) * 64 + kt * 32 + q * 8);
#pragma unroll
      for (int mt = 0; mt < 4; mt++)
#pragma unroll
        for (int nt = 0; nt < 4; nt++)
          acc[mt][nt] = mfma_bf16(af[mt], bfv[nt], acc[mt][nt]);
    }
  }
#pragma unroll
  for (int mt = 0; mt < 4; mt++)
#pragma unroll
    for (int nt = 0; nt < 4; nt++) {
      int ng = n0 + wn * 64 + nt * 16 + c16;
      float bv = bias[ng];
#pragma unroll
      for (int r = 0; r < 4; r++) {
        long mg = m0 + wm * 64 + mt * 16 + q * 4 + r;
        float val = acc[mt][nt][r] + bv;
        if constexpr (GXF32) ((float*)Cv)[mg * 2048 + ng] = val;
        else ((u16*)Cv)[mg * 2048 + ng] = f2bf(val);
      }
    }
}

// ============================================================================
// LSTM recurrence — EXACT R8 (verified 632us twice; R11's staggered pairwise
// validation regressed: the 4 divergent spin-loops act as scheduling fences
// between MFMA clusters — control flow, not waitcnt, is the cost).
// COLUMN-SPLIT + SPLIT-K + SWAPPED-OPERAND MFMA + SENTINEL-IN-DATA EXCHANGE.
// 16 blocks = 8 pairs (4 bg x 2 dir) x 2 halves; each block owns 128 h-cols.
//  - hn64 packs 4 bf16; fsig/ftanh saturate so hn is always finite and
//    f2bf(finite) is never 0xFFFF -> u64 ~0 is an unreachable SENTINEL.
//  - hx = 4-slot ring (slot s&3), memset 0xFF per dispatch. Producer stores
//    fire-and-forget (relaxed agent atomic). No flag, no ack.
//  - Consumer ingests speculatively at step top, validates ONCE (monolithic
//    __all) after own-half MFMA; capped retry (bug -> absmax fail, no hang).
//  - Post-barrier sentinel restore of the consumed slot (512 thr = 512 u64);
//    producer rewrites 3 steps later, mutual data-dependence bounds skew.
//  - lgkm-only barrier per step; no vmcnt drain in the loop.
// ============================================================================
template <bool GXF32, bool OUTF32>
__global__ __launch_bounds__(512, 2) void k_recur(
    const void* __restrict__ gxv, const u16* __restrict__ whh,
    const float* __restrict__ mask, void* __restrict__ outv,
    unsigned long long* __restrict__ hx) {
  __shared__ u16 hls[2][16 * 136];  // own half only, [row][col] row-major
  int tid = threadIdx.x;
  int w = tid >> 6, l = tid & 63;
  int row = l & 15;        // batch row within block (D col = l&15)
  int cg = l >> 4;         // col-group; lane owns cols c4..c4+3 of its tile
  int c4 = cg * 4;
  int blk = blockIdx.x;
  int pair = blk & 7, half = blk >> 3;
  int bg = pair >> 1, d = pair & 1;
  int b0 = bg * 16;
  int ht = half * 8 + w;                 // global h-coltile 0..15
  const u16* Wd = whh + d * (1024 * 256);
  constexpr unsigned long long SEN = ~0ull;

  for (int i = tid; i < 16 * 136; i += 512) hls[0][i] = 0;

  // Weight fragments: [g*8+j], j<4 own-half k-tiles, j>=4 partner-half.
  short8 Breg[32];
#pragma unroll
  for (int g = 0; g < 4; g++)
#pragma unroll
    for (int j = 0; j < 8; j++) {
      int ktg = (j < 4) ? (half * 4 + j) : ((half ^ 1) * 4 + (j - 4));
      Breg[g * 8 + j] =
          *(const short8*)(Wd + ((g * 16 + ht) * 16 + row) * 256 + ktg * 32 + cg * 8);
    }

  float c_[4] = {0.f, 0.f, 0.f, 0.f};
  unsigned long long hp64 = 0ull;  // this lane's previous 4 h-values (bf16 x4)
  __syncthreads();

  const float* gxf = (const float*)gxv;
  const u16* gxh = (const u16*)gxv;
  float* outf = (float*)outv;
  u16* outh = (u16*)outv;

  // lane-invariant bases
  int grow = b0 + row;                                   // global batch row
  const float* mrowp = mask + grow * 256;
  size_t gxbase = (size_t)grow * 524288 + d * 1024 + ht * 16 + c4;
  long obase = ((long)grow * 256) * 512 + d * 256 + ht * 16 + c4;

  using GxT = std::conditional_t<GXF32, float4v, unsigned long long>;
  GxT gxc[4], gxn[4];
  float mcur, mnxt;

  // preamble: load gx(t0) + mask(t0)
  {
    int t0 = d ? 255 : 0;
    mcur = mrowp[t0];
#pragma unroll
    for (int g = 0; g < 4; g++) {
      if constexpr (GXF32)
        gxc[g] = *(const float4v*)(gxf + gxbase + (size_t)t0 * 2048 + g * 256);
      else
        gxc[g] = *(const unsigned long long*)(gxh + gxbase + (size_t)t0 * 2048 + g * 256);
    }
  }

#pragma unroll 1
  for (int s = 0; s < 256; s++) {
    int t = d ? (255 - s) : s;
    const u16* hrd = hls[s & 1];
    u16* hwr = hls[(s & 1) ^ 1];

    // ---- ph0: SPECULATIVE partner ingest (validity checked after ph1) ----
    unsigned long long pv0 = 0, pv1 = 0, pv2 = 0, pv3 = 0,
                       pv4 = 0, pv5 = 0, pv6 = 0, pv7 = 0;
    const unsigned long long* ps = nullptr;
    if (s > 0) {
      ps = hx + ((size_t)(((s - 1) & 3) * 8 + pair) * 2 + (half ^ 1)) * 512;
      pv0 = __hip_atomic_load(&ps[(0 * 8 + cg * 2 + 0) * 16 + row], __ATOMIC_RELAXED, __HIP_MEMORY_SCOPE_AGENT);
      pv1 = __hip_atomic_load(&ps[(0 * 8 + cg * 2 + 1) * 16 + row], __ATOMIC_RELAXED, __HIP_MEMORY_SCOPE_AGENT);
      pv2 = __hip_atomic_load(&ps[(1 * 8 + cg * 2 + 0) * 16 + row], __ATOMIC_RELAXED, __HIP_MEMORY_SCOPE_AGENT);
      pv3 = __hip_atomic_load(&ps[(1 * 8 + cg * 2 + 1) * 16 + row], __ATOMIC_RELAXED, __HIP_MEMORY_SCOPE_AGENT);
      pv4 = __hip_atomic_load(&ps[(2 * 8 + cg * 2 + 0) * 16 + row], __ATOMIC_RELAXED, __HIP_MEMORY_SCOPE_AGENT);
      pv5 = __hip_atomic_load(&ps[(2 * 8 + cg * 2 + 1) * 16 + row], __ATOMIC_RELAXED, __HIP_MEMORY_SCOPE_AGENT);
      pv6 = __hip_atomic_load(&ps[(3 * 8 + cg * 2 + 0) * 16 + row], __ATOMIC_RELAXED, __HIP_MEMORY_SCOPE_AGENT);
      pv7 = __hip_atomic_load(&ps[(3 * 8 + cg * 2 + 1) * 16 + row], __ATOMIC_RELAXED, __HIP_MEMORY_SCOPE_AGENT);
    }
    __builtin_amdgcn_sched_barrier(0);  // loads issued before the MFMA body

    // ---- ph1: own-half-K MFMA (W as A, h as B); covers ingest latency ----
    float4v acc[4];
#pragma unroll
    for (int g = 0; g < 4; g++) acc[g] = (float4v){0.f, 0.f, 0.f, 0.f};
#pragma unroll
    for (int ktl = 0; ktl < 4; ktl++) {
      short8 b = *(const short8*)(hrd + row * 136 + ktl * 32 + cg * 8);
#pragma unroll
      for (int g = 0; g < 4; g++)
        acc[g] = mfma_bf16(Breg[g * 8 + ktl], b, acc[g]);
    }

    // ---- ph2: validate speculative data; retry on sentinel (rare) ----
    if (s > 0) {
      unsigned cnt = 0;
      while (!__all(pv0 != SEN && pv1 != SEN && pv2 != SEN && pv3 != SEN &&
                    pv4 != SEN && pv5 != SEN && pv6 != SEN && pv7 != SEN)) {
        if (++cnt > 400000u) break;  // ingests NaN -> absmax fail, no hang
        __builtin_amdgcn_s_sleep(1);
        pv0 = __hip_atomic_load(&ps[(0 * 8 + cg * 2 + 0) * 16 + row], __ATOMIC_RELAXED, __HIP_MEMORY_SCOPE_AGENT);
        pv1 = __hip_atomic_load(&ps[(0 * 8 + cg * 2 + 1) * 16 + row], __ATOMIC_RELAXED, __HIP_MEMORY_SCOPE_AGENT);
        pv2 = __hip_atomic_load(&ps[(1 * 8 + cg * 2 + 0) * 16 + row], __ATOMIC_RELAXED, __HIP_MEMORY_SCOPE_AGENT);
        pv3 = __hip_atomic_load(&ps[(1 * 8 + cg * 2 + 1) * 16 + row], __ATOMIC_RELAXED, __HIP_MEMORY_SCOPE_AGENT);
        pv4 = __hip_atomic_load(&ps[(2 * 8 + cg * 2 + 0) * 16 + row], __ATOMIC_RELAXED, __HIP_MEMORY_SCOPE_AGENT);
        pv5 = __hip_atomic_load(&ps[(2 * 8 + cg * 2 + 1) * 16 + row], __ATOMIC_RELAXED, __HIP_MEMORY_SCOPE_AGENT);
        pv6 = __hip_atomic_load(&ps[(3 * 8 + cg * 2 + 0) * 16 + row], __ATOMIC_RELAXED, __HIP_MEMORY_SCOPE_AGENT);
        pv7 = __hip_atomic_load(&ps[(3 * 8 + cg * 2 + 1) * 16 + row], __ATOMIC_RELAXED, __HIP_MEMORY_SCOPE_AGENT);
      }
      // ---- ph3: partner-half-K MFMA from ingest registers ----
      union U { unsigned long long u[2]; short8 s8; };
      U u0, u1, u2, u3;
      u0.u[0] = pv0; u0.u[1] = pv1;
      u1.u[0] = pv2; u1.u[1] = pv3;
      u2.u[0] = pv4; u2.u[1] = pv5;
      u3.u[0] = pv6; u3.u[1] = pv7;
#pragma unroll
      for (int g = 0; g < 4; g++) acc[g] = mfma_bf16(Breg[g * 8 + 4], u0.s8, acc[g]);
#pragma unroll
      for (int g = 0; g < 4; g++) acc[g] = mfma_bf16(Breg[g * 8 + 5], u1.s8, acc[g]);
#pragma unroll
      for (int g = 0; g < 4; g++) acc[g] = mfma_bf16(Breg[g * 8 + 6], u2.s8, acc[g]);
#pragma unroll
      for (int g = 0; g < 4; g++) acc[g] = mfma_bf16(Breg[g * 8 + 7], u3.s8, acc[g]);
    }

    // ---- ph4: nonlinearity; lane owns row `grow`, h-cols ht*16+c4..+3 ----
    float mt = mcur, mo = 1.f - mcur;
    float hnv[4];
    unsigned long long hn64 = 0ull;
#pragma unroll
    for (int r = 0; r < 4; r++) {
      float gi, gf, gg, go;
      if constexpr (GXF32) {
        gi = gxc[0][r]; gf = gxc[1][r]; gg = gxc[2][r]; go = gxc[3][r];
      } else {
        gi = bf2f((u16)(gxc[0] >> (r * 16)));
        gf = bf2f((u16)(gxc[1] >> (r * 16)));
        gg = bf2f((u16)(gxc[2] >> (r * 16)));
        go = bf2f((u16)(gxc[3] >> (r * 16)));
      }
      float iv = fsig(acc[0][r] + gi);
      float fv = fsig(acc[1][r] + gf);
      float gv = ftanh(acc[2][r] + gg);
      float ov = fsig(acc[3][r] + go);
      float hpo = bf2f((u16)(hp64 >> (r * 16)));
      float cn = fv * c_[r] + iv * gv;
      float hn = ov * ftanh(cn);
      hn = mt * hn + mo * hpo;
      cn = mt * cn + mo * c_[r];
      c_[r] = cn;
      hnv[r] = hn;
      hn64 |= ((unsigned long long)f2bf(hn)) << (r * 16);
    }

    // ---- ph5: publish h(s), outputs, prefetch gx(t+1), restore sentinel ---
    if (s < 255) {
      // hx store: fire-and-forget (relaxed atomic -> LLC; data IS the signal)
      __hip_atomic_store(
          &hx[((size_t)((s & 3) * 8 + pair) * 2 + half) * 512 + (w * 4 + cg) * 16 + row],
          hn64, __ATOMIC_RELAXED, __HIP_MEMORY_SCOPE_AGENT);
      // own h -> hls (one b64; read by next step's ph1 b128s)
      *(unsigned long long*)(hwr + row * 136 + w * 16 + c4) = hn64;
      // output store (single vector op)
      if constexpr (OUTF32) {
        float4v ov4 = {hnv[0], hnv[1], hnv[2], hnv[3]};
        *(float4v*)(outf + obase + (long)t * 512) = ov4;
      } else {
        *(unsigned long long*)(outh + obase + (long)t * 512) = hn64;
      }
      // prefetch next-step gx + mask (consumed next ph4; ~full-step cover)
      int tn = d ? (254 - s) : (s + 1);
      mnxt = mrowp[tn];
#pragma unroll
      for (int g = 0; g < 4; g++) {
        if constexpr (GXF32)
          gxn[g] = *(const float4v*)(gxf + gxbase + (size_t)tn * 2048 + g * 256);
        else
          gxn[g] = *(const unsigned long long*)(gxh + gxbase + (size_t)tn * 2048 + g * 256);
      }
      __builtin_amdgcn_sched_barrier(0);
      // lgkm-only barrier: hls visibility; NO vmcnt drain in the loop
      asm volatile("s_waitcnt lgkmcnt(0)" ::: "memory");
      __builtin_amdgcn_s_barrier();
      __builtin_amdgcn_sched_barrier(0);
      // restore sentinel on the slot consumed this step (all waves are past
      // their ingest-check: the barrier above proves it). 512 thr = 512 u64.
      if (s > 0) {
        __hip_atomic_store(
            &hx[((size_t)(((s - 1) & 3) * 8 + pair) * 2 + (half ^ 1)) * 512 + tid],
            SEN, __ATOMIC_RELAXED, __HIP_MEMORY_SCOPE_AGENT);
      }
#pragma unroll
      for (int g = 0; g < 4; g++) gxc[g] = gxn[g];
      mcur = mnxt;
    } else {
      // last step: outputs only
      if constexpr (OUTF32) {
        float4v ov4 = {hnv[0], hnv[1], hnv[2], hnv[3]};
        *(float4v*)(outf + obase + (long)t * 512) = ov4;
      } else {
        *(unsigned long long*)(outh + obase + (long)t * 512) = hn64;
      }
    }
    hp64 = hn64;
  }
}

// ============================================================================
extern "C" void kernel_launch(void* const* d_in, const int* in_sizes, int n_in,
                              void* d_out, int out_size, void* d_ws, size_t ws_size,
                              hipStream_t stream) {
  const int* iw = (const int*)d_in[0];
  const int* ic = (const int*)d_in[1];
  const int* ip = (const int*)d_in[2];
  const float* mask = (const float*)d_in[3];
  const float* ew = (const float*)d_in[4];
  const float* ec = (const float*)d_in[5];
  const float* ep = (const float*)d_in[6];
  const float* cw = (const float*)d_in[7];
  const float* cb = (const float*)d_in[8];
  const float* wih[3] = {(const float*)d_in[9], (const float*)d_in[12], (const float*)d_in[15]};
  const float* whh[3] = {(const float*)d_in[10], (const float*)d_in[13], (const float*)d_in[16]};
  const float* bs[3] = {(const float*)d_in[11], (const float*)d_in[14], (const float*)d_in[17]};

  char* ws = (char*)d_ws;
  size_t szX0 = (size_t)16384 * 512 * 2;
  size_t szGXf = (size_t)16384 * 2048 * 4;
  size_t szWIH = (size_t)2048 * 512 * 2;
  size_t szWHH = (size_t)2 * 1024 * 256 * 2;
  size_t szPROJ = 60032;
  size_t szHX = (size_t)4 * 8 * 2 * 4096;   // 4-slot ring x pair x half = 256KB
  bool f32gx = ws_size >= szX0 + szGXf + szWIH + szWHH + szPROJ + szHX;

  size_t off = 0;
  u16* X0 = (u16*)(ws + off); off += szX0;
  void* GX = (void*)(ws + off); off += f32gx ? szGXf : (szGXf / 2);
  u16* WIHB = (u16*)(ws + off); off += szWIH;
  u16* WHHB = (u16*)(ws + off); off += szWHH;
  u16* PROJ = (u16*)(ws + off); off += szPROJ;
  unsigned long long* HX = (unsigned long long*)(ws + off);
  u16* X1 = (u16*)d_out;  // bf16 staging in d_out; dead before final f32 write

  hipLaunchKernelGGL(k_proj, dim3(100), dim3(320), 0, stream, ec, cw, PROJ);
  hipLaunchKernelGGL(k_embed, dim3(16384), dim3(512), 0, stream, iw, ip, ew, ep, X0);
  hipLaunchKernelGGL(k_charconv, dim3(1024), dim3(128), 0, stream, ic, PROJ, cb, X0);

  const u16* Xin[3] = {X0, X1, X0};
  void* Xout[3] = {(void*)X1, (void*)X0, d_out};
  int Kin[3] = {500, 512, 512};

  for (int lyr = 0; lyr < 3; lyr++) {
    hipLaunchKernelGGL(k_cvt_wih, dim3(4096), dim3(256), 0, stream, wih[lyr], WIHB, Kin[lyr]);
    hipLaunchKernelGGL(k_cvt_whh, dim3(2048), dim3(256), 0, stream, whh[lyr], WHHB);
    hipMemsetAsync(HX, 0xFF, szHX, stream);  // all slots -> sentinel (replay-safe)
    if (f32gx) {
      hipLaunchKernelGGL((k_gemm<true>), dim3(16, 128), dim3(256), 0, stream,
                         Xin[lyr], WIHB, bs[lyr], GX);
      if (lyr < 2)
        hipLaunchKernelGGL((k_recur<true, false>), dim3(16), dim3(512), 0, stream,
                           GX, WHHB, mask, Xout[lyr], HX);
      else
        hipLaunchKernelGGL((k_recur<true, true>), dim3(16), dim3(512), 0, stream,
                           GX, WHHB, mask, Xout[lyr], HX);
    } else {
      hipLaunchKernelGGL((k_gemm<false>), dim3(16, 128), dim3(256), 0, stream,
                         Xin[lyr], WIHB, bs[lyr], GX);
      if (lyr < 2)
        hipLaunchKernelGGL((k_recur<false, false>), dim3(16), dim3(512), 0, stream,
                           GX, WHHB, mask, Xout[lyr], HX);
      else
        hipLaunchKernelGGL((k_recur<false, true>), dim3(16), dim3(512), 0, stream,
                           GX, WHHB, mask, Xout[lyr], HX);
    }
  }
}